// Round 1
// 9785.264 us; speedup vs baseline: 1.6172x; 1.6172x over previous
//
#include <hip/hip_runtime.h>
#include <hip/hip_bf16.h>
#include <cmath>

#define NB 8
#define NS 512
#define NHID 768
#define NHEAD 12
#define NL 12
#define NDH 64
#define NFF 3072
#define NTOK (NB*NS)
#define LN_EPS 1e-7f
#define NREL 1023

typedef _Float16 h8 __attribute__((ext_vector_type(8)));
typedef float f4 __attribute__((ext_vector_type(4)));

static __device__ __forceinline__ float dot4(float4 a, float4 b){
  return a.x*b.x + a.y*b.y + a.z*b.z + a.w*b.w;
}

// ---------------- embedding: gather + LN + mask ----------------
__global__ __launch_bounds__(256) void emb_kernel(
    const float* __restrict__ we, const float* __restrict__ pe,
    const float* __restrict__ g, const float* __restrict__ bvec,
    const int* __restrict__ ids, const int* __restrict__ msk, float* __restrict__ out)
{
  const int token = blockIdx.x, tid = threadIdx.x;
  const int s = token & (NS-1);
  __shared__ float red[256];
  const int id = ids[token];
  const float* wp = we + (size_t)id*NHID;
  const float* pp = pe + (size_t)s*NHID;
  float e[3]; float sum = 0.f;
  #pragma unroll
  for (int j=0;j<3;j++){ int d = tid + j*256; e[j] = wp[d] + pp[d]; sum += e[j]; }
  red[tid]=sum; __syncthreads();
  for (int o=128;o>0;o>>=1){ if (tid<o) red[tid]+=red[tid+o]; __syncthreads(); }
  const float mu = red[0]*(1.0f/NHID); __syncthreads();
  float vs=0.f;
  #pragma unroll
  for (int j=0;j<3;j++){ float d=e[j]-mu; vs += d*d; }
  red[tid]=vs; __syncthreads();
  for (int o=128;o>0;o>>=1){ if (tid<o) red[tid]+=red[tid+o]; __syncthreads(); }
  const float rstd = 1.0f/sqrtf(red[0]*(1.0f/NHID)+LN_EPS);
  const float mf = (float)msk[token];
  #pragma unroll
  for (int j=0;j<3;j++){
    int d = tid + j*256;
    out[(size_t)token*NHID + d] = ((e[j]-mu)*rstd*g[d] + bvec[d])*mf;
  }
}

// ---------------- LayerNorm (f32 in, f32 out) ----------------
__global__ __launch_bounds__(256) void ln_kernel(
    const float* __restrict__ X, const float* __restrict__ g, const float* __restrict__ bvec,
    float* __restrict__ out)
{
  const int token = blockIdx.x, tid = threadIdx.x;
  __shared__ float red[256];
  const float* x = X + (size_t)token*NHID;
  float e[3]; float sum=0.f;
  #pragma unroll
  for (int j=0;j<3;j++){ e[j]=x[tid+j*256]; sum+=e[j]; }
  red[tid]=sum; __syncthreads();
  for (int o=128;o>0;o>>=1){ if (tid<o) red[tid]+=red[tid+o]; __syncthreads(); }
  const float mu = red[0]*(1.0f/NHID); __syncthreads();
  float vs=0.f;
  #pragma unroll
  for (int j=0;j<3;j++){ float d=e[j]-mu; vs+=d*d; }
  red[tid]=vs; __syncthreads();
  for (int o=128;o>0;o>>=1){ if (tid<o) red[tid]+=red[tid+o]; __syncthreads(); }
  const float rstd = 1.0f/sqrtf(red[0]*(1.0f/NHID)+LN_EPS);
  #pragma unroll
  for (int j=0;j<3;j++){
    int d = tid + j*256;
    out[(size_t)token*NHID + d] = (e[j]-mu)*rstd*g[d] + bvec[d];
  }
}

// ---------------- weight prep: W[K][N] f32 -> Wt[N][K] f16 hi/lo, k-tiled (32) ----------------
// Layout (halves): out[(t*N + n)*32 + ((c ^ (n&3))*8) + j] = W[t*32 + c*8 + j][n]
// i.e. per (k-tile, n) a 64B row of 4 16B chunks with XOR-swizzle baked in, so GEMM
// LDS staging is a straight linear copy and frag ds_read_b128 is bank-conflict-free.
__global__ __launch_bounds__(256) void wprep_kernel(
    const float* __restrict__ W0, const float* __restrict__ W1, const float* __restrict__ W2,
    const float* __restrict__ W3, const float* __restrict__ W4, const float* __restrict__ W5,
    _Float16* __restrict__ OH, _Float16* __restrict__ OL)
{
  const int z = blockIdx.z;
  const int K_ = (z==5)?NFF:NHID;
  const int N_ = (z==4)?NFF:NHID;
  const int tI = blockIdx.y, nI = blockIdx.x;
  if (tI*32 >= K_ || nI*64 >= N_) return;
  const float* W = (z==0)?W0:(z==1)?W1:(z==2)?W2:(z==3)?W3:(z==4)?W4:W5;
  const size_t off = (z<5) ? (size_t)z*589824 : (size_t)4718592;
  __shared__ float T[32][66];
  const int tid = threadIdx.x;
  {
    const int kk = tid>>3, n8 = (tid&7)*8;
    const float* src = W + (size_t)(tI*32+kk)*N_ + nI*64 + n8;
    float4 v0 = *(const float4*)src;
    float4 v1 = *(const float4*)(src+4);
    T[kk][n8+0]=v0.x; T[kk][n8+1]=v0.y; T[kk][n8+2]=v0.z; T[kk][n8+3]=v0.w;
    T[kk][n8+4]=v1.x; T[kk][n8+5]=v1.y; T[kk][n8+6]=v1.z; T[kk][n8+7]=v1.w;
  }
  __syncthreads();
  const int n = tid>>2, c = tid&3;
  h8 hv, lv;
  #pragma unroll
  for (int j=0;j<8;j++){
    float x = T[c*8+j][n];
    _Float16 h = (_Float16)x;
    hv[j] = h;
    lv[j] = (_Float16)(x - (float)h);
  }
  _Float16* drow = OH + off + ((size_t)tI*N_ + (size_t)nI*64 + n)*32 + ((c ^ (n&3))*8);
  *(h8*)drow = hv;
  *(h8*)(OL + (drow - OH)) = lv;
}

// ---------------- split-f16 MFMA GEMM: C[M,N] = epi(A@W + bias) ----------------
// A f32 converted hi/lo in staging; W pre-converted/transposed/swizzled by wprep.
// 3 MFMAs per frag pair: ah*bh + al*bh + ah*bl  (al*bl ~2^-24, dropped).
// EPI: 0=none, 1=exact GELU, 2=+res
template<int EPI, int BN>
__global__ __launch_bounds__(256,2) void gemm_mfma(
    const float* __restrict__ A, const _Float16* __restrict__ WH, const _Float16* __restrict__ WL,
    const float* __restrict__ bias, const float* __restrict__ res, float* __restrict__ outp,
    int M, int N, int K)
{
  constexpr int NF = BN/32;                 // frags per wave along N
  __shared__ __align__(16) _Float16 Ah[128*32];
  __shared__ __align__(16) _Float16 Al[128*32];
  __shared__ __align__(16) _Float16 Bh[BN*32];
  __shared__ __align__(16) _Float16 Bl[BN*32];
  const int tid = threadIdx.x;
  const int w = tid>>6, l = tid&63;
  const int wm = w>>1, wn = w&1, lr = l&15, lc = l>>4;
  const int bm = blockIdx.y*128, bn = blockIdx.x*BN;
  const int T = K>>5;
  f4 acc[4][NF] = {};

  // A staging: thread -> (row sr, 16-k half sk)
  const int sr = tid>>1, sk = (tid&1)<<4;
  const float* aptr = A + (size_t)(bm+sr)*K + sk;
  _Float16* arH = Ah + sr*32;
  _Float16* arL = Al + sr*32;
  const int c0 = sk>>3;
  const int p0 = ((c0  ) ^ (sr&3))<<3;
  const int p1 = ((c0+1) ^ (sr&3))<<3;
  // frag read bases (chunk-swizzled)
  const int fsw = (lc ^ (lr&3))<<3;
  const int aBase = (wm*64 + lr)*32 + fsw;
  const int bBase = (wn*(BN/2) + lr)*32 + fsw;

  float4 ga0, ga1, ga2, ga3;
  uint4 gb0h = {}, gb0l = {}, gb1h = {}, gb1l = {};

  auto loadg = [&](int t){
    const float* ap = aptr + t*32;
    ga0 = *(const float4*)(ap);
    ga1 = *(const float4*)(ap+4);
    ga2 = *(const float4*)(ap+8);
    ga3 = *(const float4*)(ap+12);
    const uint4* bsH = (const uint4*)(WH + ((size_t)t*N + bn)*32);
    const uint4* bsL = (const uint4*)(WL + ((size_t)t*N + bn)*32);
    gb0h = bsH[tid]; gb0l = bsL[tid];
    if (NF==4){ gb1h = bsH[tid+256]; gb1l = bsL[tid+256]; }
  };
  loadg(0);

  for (int t=0; t<T; ++t){
    // convert A regs -> hi/lo halves
    float xs[16] = {ga0.x,ga0.y,ga0.z,ga0.w, ga1.x,ga1.y,ga1.z,ga1.w,
                    ga2.x,ga2.y,ga2.z,ga2.w, ga3.x,ga3.y,ga3.z,ga3.w};
    h8 hv0, hv1, lv0, lv1;
    #pragma unroll
    for (int j=0;j<8;j++){
      _Float16 h0 = (_Float16)xs[j];
      hv0[j] = h0; lv0[j] = (_Float16)(xs[j] - (float)h0);
      _Float16 h1 = (_Float16)xs[8+j];
      hv1[j] = h1; lv1[j] = (_Float16)(xs[8+j] - (float)h1);
    }
    __syncthreads();                       // previous iteration's frag reads done
    *(h8*)(arH+p0) = hv0; *(h8*)(arH+p1) = hv1;
    *(h8*)(arL+p0) = lv0; *(h8*)(arL+p1) = lv1;
    ((uint4*)Bh)[tid] = gb0h; ((uint4*)Bl)[tid] = gb0l;
    if (NF==4){ ((uint4*)Bh)[tid+256] = gb1h; ((uint4*)Bl)[tid+256] = gb1l; }
    __syncthreads();                       // staging visible
    if (t+1 < T) loadg(t+1);               // prefetch under MFMA phase

    h8 ahv[4], alv[4];
    #pragma unroll
    for (int mf=0; mf<4; ++mf){
      ahv[mf] = *(const h8*)(Ah + aBase + mf*512);
      alv[mf] = *(const h8*)(Al + aBase + mf*512);
    }
    #pragma unroll
    for (int nf=0; nf<NF; ++nf){
      h8 bhv = *(const h8*)(Bh + bBase + nf*512);
      h8 blv = *(const h8*)(Bl + bBase + nf*512);
      #pragma unroll
      for (int mf=0; mf<4; ++mf){
        acc[mf][nf] = __builtin_amdgcn_mfma_f32_16x16x32_f16(ahv[mf], bhv, acc[mf][nf], 0,0,0);
        acc[mf][nf] = __builtin_amdgcn_mfma_f32_16x16x32_f16(alv[mf], bhv, acc[mf][nf], 0,0,0);
        acc[mf][nf] = __builtin_amdgcn_mfma_f32_16x16x32_f16(ahv[mf], blv, acc[mf][nf], 0,0,0);
      }
    }
  }
  // epilogue: C/D layout col=lane&15, row=(lane>>4)*4+reg  [m89-verified]
  #pragma unroll
  for (int nf=0; nf<NF; ++nf){
    const int n = bn + wn*(BN/2) + nf*16 + lr;
    const float bb = bias[n];
    #pragma unroll
    for (int mf=0; mf<4; ++mf){
      #pragma unroll
      for (int r=0; r<4; ++r){
        const int m = bm + wm*64 + mf*16 + lc*4 + r;
        float v = acc[mf][nf][r] + bb;
        if (EPI==1) v = 0.5f*v*(1.0f + erff(v*0.7071067811865476f));
        if (EPI==2) v += res[(size_t)m*N + n];
        outp[(size_t)m*N + n] = v;
      }
    }
  }
}

// ---------------- rel-position pre-gather: PKg[h][r][d] = PK[idx(r-511)][h*64+d] ----------------
__global__ __launch_bounds__(64) void relgather_kernel(
    const float* __restrict__ PKb, const float* __restrict__ PQb,
    float* __restrict__ PKg, float* __restrict__ PQg)
{
  const int r = blockIdx.x;       // 0..1022
  const int h = blockIdx.y;       // 0..11
  const int d = threadIdx.x;      // 0..63
  const int rel = r - 511;
  const int sg = (rel>0) - (rel<0);
  const float ap = (rel<128 && rel>-128) ? 127.0f : fabsf((float)rel);
  int bucket;
  if (ap <= 128.0f) bucket = rel;
  else bucket = (int)((ceilf(logf(ap*(1.0f/128.0f))/1.3843393f*127.0f)+128.0f)*(float)sg);
  const int idx = min(max(bucket+256,0),511);
  const size_t src = (size_t)idx*NHID + h*NDH + d;
  const size_t dst = ((size_t)h*NREL + r)*NDH + d;
  PKg[dst] = PKb[src];
  PQg[dst] = PQb[src];
}

// ---------------- tiled flash-style disentangled attention ----------------
// block = (qtile of 32, h, b). score(q,k) = Q.K + Q.PKg[q-k] + K.PQg[q-k]
#define QT 32
#define KT 32
#define RT 63
__global__ __launch_bounds__(256) void attn_kernel(
    const float* __restrict__ Q, const float* __restrict__ K, const float* __restrict__ V,
    const float* __restrict__ PKg, const float* __restrict__ PQg,
    const int* __restrict__ msk, float* __restrict__ Ctx)
{
  __shared__ __align__(16) float Qs[QT][68];
  __shared__ __align__(16) float Ks[KT][68];
  __shared__ __align__(16) float Vs[KT][68];
  __shared__ __align__(16) float PKs[RT][68];
  __shared__ __align__(16) float PQs[RT][68];
  __shared__ __align__(16) float Ss[QT][36];
  __shared__ int mqS[QT];
  __shared__ int mkS[KT];
  const int tid = threadIdx.x;
  const int qt = blockIdx.x, h = blockIdx.y, b = blockIdx.z;
  const int q0 = qt*QT;
  for (int i = tid; i < QT*16; i += 256){
    int row = i>>4, c = (i&15)*4;
    *(float4*)&Qs[row][c] = *(const float4*)&Q[(size_t)(b*NS + q0 + row)*NHID + h*NDH + c];
  }
  if (tid < QT) mqS[tid] = msk[b*NS + q0 + tid];

  const int tx = tid & 15, ty = tid >> 4;
  const int sq = tid >> 3, sj = tid & 7;
  const int dj = sj*8;
  float m_i = -3.4e38f, l_i = 0.f;
  float ctx[8] = {0,0,0,0,0,0,0,0};

  for (int kt = 0; kt < NS/KT; kt++){
    const int k0c = kt*KT;
    __syncthreads();
    for (int i = tid; i < KT*16; i += 256){
      int row = i>>4, c = (i&15)*4;
      size_t gb = (size_t)(b*NS + k0c + row)*NHID + h*NDH + c;
      *(float4*)&Ks[row][c] = *(const float4*)&K[gb];
      *(float4*)&Vs[row][c] = *(const float4*)&V[gb];
    }
    const int rstart = q0 - k0c + 480;
    for (int i = tid; i < RT*16; i += 256){
      int row = i>>4, c = (i&15)*4;
      size_t gb = ((size_t)h*NREL + rstart + row)*NDH + c;
      *(float4*)&PKs[row][c] = *(const float4*)&PKg[gb];
      *(float4*)&PQs[row][c] = *(const float4*)&PQg[gb];
    }
    if (tid < KT) mkS[tid] = msk[b*NS + k0c + tid];
    __syncthreads();
    const int qa = ty*2, kb = tx*2;
    const int rc = qa - kb + 31;
    float s00=0,s01=0,s10=0,s11=0;
    #pragma unroll
    for (int c = 0; c < 64; c += 4){
      float4 qv0 = *(const float4*)&Qs[qa  ][c];
      float4 qv1 = *(const float4*)&Qs[qa+1][c];
      float4 kv0 = *(const float4*)&Ks[kb  ][c];
      float4 kv1 = *(const float4*)&Ks[kb+1][c];
      float4 pk0 = *(const float4*)&PKs[rc-1][c];
      float4 pk1 = *(const float4*)&PKs[rc  ][c];
      float4 pk2 = *(const float4*)&PKs[rc+1][c];
      float4 pq0 = *(const float4*)&PQs[rc-1][c];
      float4 pq1 = *(const float4*)&PQs[rc  ][c];
      float4 pq2 = *(const float4*)&PQs[rc+1][c];
      s00 += dot4(qv0,kv0) + dot4(qv0,pk1) + dot4(kv0,pq1);
      s01 += dot4(qv0,kv1) + dot4(qv0,pk0) + dot4(kv1,pq0);
      s10 += dot4(qv1,kv0) + dot4(qv1,pk2) + dot4(kv0,pq2);
      s11 += dot4(qv1,kv1) + dot4(qv1,pk1) + dot4(kv1,pq1);
    }
    const float SC = 0.07216878364870322f;
    const int mq0=mqS[qa], mq1=mqS[qa+1], mk0=mkS[kb], mk1=mkS[kb+1];
    Ss[qa  ][kb  ] = (mq0&&mk0)? s00*SC : -3.4e38f;
    Ss[qa  ][kb+1] = (mq0&&mk1)? s01*SC : -3.4e38f;
    Ss[qa+1][kb  ] = (mq1&&mk0)? s10*SC : -3.4e38f;
    Ss[qa+1][kb+1] = (mq1&&mk1)? s11*SC : -3.4e38f;
    __syncthreads();
    float4 sp = *(const float4*)&Ss[sq][sj*4];
    float tm = fmaxf(fmaxf(sp.x,sp.y), fmaxf(sp.z,sp.w));
    tm = fmaxf(tm, __shfl_xor(tm, 1, 8));
    tm = fmaxf(tm, __shfl_xor(tm, 2, 8));
    tm = fmaxf(tm, __shfl_xor(tm, 4, 8));
    const float m_new = fmaxf(m_i, tm);
    const float alpha = expf(m_i - m_new);
    float p0 = expf(sp.x - m_new), p1 = expf(sp.y - m_new);
    float p2 = expf(sp.z - m_new), p3 = expf(sp.w - m_new);
    *(float4*)&Ss[sq][sj*4] = make_float4(p0,p1,p2,p3);
    float ts = p0+p1+p2+p3;
    ts += __shfl_xor(ts, 1, 8);
    ts += __shfl_xor(ts, 2, 8);
    ts += __shfl_xor(ts, 4, 8);
    l_i = l_i*alpha + ts;
    m_i = m_new;
    __syncthreads();
    #pragma unroll
    for (int e=0;e<8;e++) ctx[e] *= alpha;
    #pragma unroll
    for (int k=0;k<KT;k+=4){
      float4 pv = *(const float4*)&Ss[sq][k];
      #pragma unroll
      for (int kk=0;kk<4;kk++){
        const float p = (kk==0)?pv.x:(kk==1)?pv.y:(kk==2)?pv.z:pv.w;
        float4 va = *(const float4*)&Vs[k+kk][dj];
        float4 vb = *(const float4*)&Vs[k+kk][dj+4];
        ctx[0]+=p*va.x; ctx[1]+=p*va.y; ctx[2]+=p*va.z; ctx[3]+=p*va.w;
        ctx[4]+=p*vb.x; ctx[5]+=p*vb.y; ctx[6]+=p*vb.z; ctx[7]+=p*vb.w;
      }
    }
  }
  const float inv = (l_i > 0.f && m_i > -1e30f && mqS[sq]) ? 1.0f/l_i : 0.0f;
  const size_t orow = (size_t)(b*NS + q0 + sq)*NHID + h*NDH + dj;
  #pragma unroll
  for (int e=0;e<8;e++) Ctx[orow+e] = ctx[e]*inv;
}

extern "C" void kernel_launch(void* const* d_in, const int* in_sizes, int n_in,
                              void* d_out, int out_size, void* d_ws, size_t ws_size,
                              hipStream_t stream)
{
  const float* word_emb=(const float*)d_in[0];
  const float* pos_emb =(const float*)d_in[1];
  const float* emb_g   =(const float*)d_in[2];
  const float* emb_b   =(const float*)d_in[3];
  const float* rel_emb =(const float*)d_in[4];
  const float* Wq=(const float*)d_in[5];  const float* bq=(const float*)d_in[6];
  const float* Wk=(const float*)d_in[7];  const float* bk=(const float*)d_in[8];
  const float* Wv=(const float*)d_in[9];  const float* bvv=(const float*)d_in[10];
  const float* Wo=(const float*)d_in[11]; const float* bo=(const float*)d_in[12];
  const float* g1=(const float*)d_in[13]; const float* b1=(const float*)d_in[14];
  const float* Wi=(const float*)d_in[15]; const float* bi=(const float*)d_in[16];
  const float* Wo2=(const float*)d_in[17];const float* bo2=(const float*)d_in[18];
  const float* g2=(const float*)d_in[19]; const float* b2=(const float*)d_in[20];
  const int* ids  =(const int*)d_in[21];
  const int* amask=(const int*)d_in[22];

  char* p = (char*)d_ws;
  auto alloc = [&](size_t bytes)->char*{ char* r = p; p += (bytes + 255) & ~(size_t)255; return r; };
  float* Hb  = (float*)alloc((size_t)NTOK*NHID*4);
  float* H1  = (float*)alloc((size_t)NTOK*NHID*4);
  float* Xb  = (float*)alloc((size_t)NTOK*NHID*4);
  float* FFb = (float*)alloc((size_t)NTOK*NFF*4);
  float* Ctxb= (float*)alloc((size_t)NTOK*NHID*4);
  float* Qb  = (float*)alloc((size_t)NTOK*NHID*4);
  float* Kb  = (float*)alloc((size_t)NTOK*NHID*4);
  float* Vb  = (float*)alloc((size_t)NTOK*NHID*4);
  float* PKb = (float*)alloc((size_t)512*NHID*4);
  float* PQb = (float*)alloc((size_t)512*NHID*4);
  float* PKg = (float*)alloc((size_t)NHEAD*NREL*NDH*4);
  float* PQg = (float*)alloc((size_t)NHEAD*NREL*NDH*4);
  _Float16* WtH = (_Float16*)alloc((size_t)7077888*2);
  _Float16* WtL = (_Float16*)alloc((size_t)7077888*2);

  // per-weight offsets (halves) inside Wt buffers: Wq,Wk,Wv,Wo,Wi,Wo2
  const size_t WO[6] = {0, 589824, 1179648, 1769472, 2359296, 4718592};

  dim3 blk(256);
  dim3 gRel(NREL, NHEAD);
  dim3 gAttn(NS/QT, NHEAD, NB);
  dim3 gPrep(48, 96, 6);               // n-tiles(64) x k-tiles(32) x 6 weights (guarded)
  dim3 gSmall(12, 4);                  // 512 x 768, BN=64
  dim3 gProj(12, 32);                  // 4096 x 768, BN=64
  dim3 gFF1(24, 32);                   // 4096 x 3072, BN=128

  emb_kernel<<<NTOK,blk,0,stream>>>(word_emb,pos_emb,emb_g,emb_b,ids,amask,Hb);

  for (int l=0; l<NL; l++){
    const float *Wq_l=Wq+(size_t)l*NHID*NHID, *bq_l=bq+(size_t)l*NHID;
    const float *Wk_l=Wk+(size_t)l*NHID*NHID, *bk_l=bk+(size_t)l*NHID;
    const float *Wv_l=Wv+(size_t)l*NHID*NHID, *bv_l=bvv+(size_t)l*NHID;
    const float *Wo_l=Wo+(size_t)l*NHID*NHID, *bo_l=bo+(size_t)l*NHID;
    const float *g1_l=g1+(size_t)l*NHID, *b1_l=b1+(size_t)l*NHID;
    const float *Wi_l=Wi+(size_t)l*NHID*NFF, *bi_l=bi+(size_t)l*NFF;
    const float *Wo2_l=Wo2+(size_t)l*NFF*NHID, *bo2_l=bo2+(size_t)l*NHID;
    const float *g2_l=g2+(size_t)l*NHID, *b2_l=b2+(size_t)l*NHID;

    // convert/transpose/swizzle this layer's 6 weight matrices to f16 hi/lo
    wprep_kernel<<<gPrep,blk,0,stream>>>(Wq_l,Wk_l,Wv_l,Wo_l,Wi_l,Wo2_l,WtH,WtL);

    // relative position projections (share_att_key=True: use Wk/Wq), then pre-gather
    gemm_mfma<0,64><<<gSmall,blk,0,stream>>>(rel_emb, WtH+WO[1], WtL+WO[1], bk_l, nullptr, PKb, 512,NHID,NHID);
    gemm_mfma<0,64><<<gSmall,blk,0,stream>>>(rel_emb, WtH+WO[0], WtL+WO[0], bq_l, nullptr, PQb, 512,NHID,NHID);
    relgather_kernel<<<gRel,dim3(64),0,stream>>>(PKb, PQb, PKg, PQg);
    // Q,K,V
    gemm_mfma<0,64><<<gProj,blk,0,stream>>>(Hb, WtH+WO[0], WtL+WO[0], bq_l, nullptr, Qb, NTOK,NHID,NHID);
    gemm_mfma<0,64><<<gProj,blk,0,stream>>>(Hb, WtH+WO[1], WtL+WO[1], bk_l, nullptr, Kb, NTOK,NHID,NHID);
    gemm_mfma<0,64><<<gProj,blk,0,stream>>>(Hb, WtH+WO[2], WtL+WO[2], bv_l, nullptr, Vb, NTOK,NHID,NHID);
    // attention
    attn_kernel<<<gAttn,blk,0,stream>>>(Qb,Kb,Vb,PKg,PQg,amask,Ctxb);
    // output proj + residual, LN1
    gemm_mfma<2,64><<<gProj,blk,0,stream>>>(Ctxb, WtH+WO[3], WtL+WO[3], bo_l, Hb, Xb, NTOK,NHID,NHID);
    ln_kernel<<<NTOK,blk,0,stream>>>(Xb, g1_l, b1_l, H1);
    // FFN
    gemm_mfma<1,128><<<gFF1,blk,0,stream>>>(H1, WtH+WO[4], WtL+WO[4], bi_l, nullptr, FFb, NTOK,NFF,NHID);
    gemm_mfma<2,64><<<gProj,blk,0,stream>>>(FFb, WtH+WO[5], WtL+WO[5], bo2_l, H1, Xb, NTOK,NHID,NFF);
    // LN2: last layer writes the final output directly
    float* dst = (l==NL-1) ? (float*)d_out : Hb;
    ln_kernel<<<NTOK,blk,0,stream>>>(Xb, g2_l, b2_l, dst);
  }
}

// Round 2
// 7381.780 us; speedup vs baseline: 2.1437x; 1.3256x over previous
//
#include <hip/hip_runtime.h>
#include <hip/hip_bf16.h>
#include <cmath>

#define NB 8
#define NS 512
#define NHID 768
#define NHEAD 12
#define NL 12
#define NDH 64
#define NFF 3072
#define NTOK (NB*NS)
#define LN_EPS 1e-7f

typedef _Float16 h8 __attribute__((ext_vector_type(8)));
typedef _Float16 h4 __attribute__((ext_vector_type(4)));
typedef float f4 __attribute__((ext_vector_type(4)));

// ---------------- embedding: gather + LN + mask ----------------
__global__ __launch_bounds__(256) void emb_kernel(
    const float* __restrict__ we, const float* __restrict__ pe,
    const float* __restrict__ g, const float* __restrict__ bvec,
    const int* __restrict__ ids, const int* __restrict__ msk, float* __restrict__ out)
{
  const int token = blockIdx.x, tid = threadIdx.x;
  const int s = token & (NS-1);
  __shared__ float red[256];
  const int id = ids[token];
  const float* wp = we + (size_t)id*NHID;
  const float* pp = pe + (size_t)s*NHID;
  float e[3]; float sum = 0.f;
  #pragma unroll
  for (int j=0;j<3;j++){ int d = tid + j*256; e[j] = wp[d] + pp[d]; sum += e[j]; }
  red[tid]=sum; __syncthreads();
  for (int o=128;o>0;o>>=1){ if (tid<o) red[tid]+=red[tid+o]; __syncthreads(); }
  const float mu = red[0]*(1.0f/NHID); __syncthreads();
  float vs=0.f;
  #pragma unroll
  for (int j=0;j<3;j++){ float d=e[j]-mu; vs += d*d; }
  red[tid]=vs; __syncthreads();
  for (int o=128;o>0;o>>=1){ if (tid<o) red[tid]+=red[tid+o]; __syncthreads(); }
  const float rstd = 1.0f/sqrtf(red[0]*(1.0f/NHID)+LN_EPS);
  const float mf = (float)msk[token];
  #pragma unroll
  for (int j=0;j<3;j++){
    int d = tid + j*256;
    out[(size_t)token*NHID + d] = ((e[j]-mu)*rstd*g[d] + bvec[d])*mf;
  }
}

// ---------------- LayerNorm (f32 in, f32 out) ----------------
__global__ __launch_bounds__(256) void ln_kernel(
    const float* __restrict__ X, const float* __restrict__ g, const float* __restrict__ bvec,
    float* __restrict__ out)
{
  const int token = blockIdx.x, tid = threadIdx.x;
  __shared__ float red[256];
  const float* x = X + (size_t)token*NHID;
  float e[3]; float sum=0.f;
  #pragma unroll
  for (int j=0;j<3;j++){ e[j]=x[tid+j*256]; sum+=e[j]; }
  red[tid]=sum; __syncthreads();
  for (int o=128;o>0;o>>=1){ if (tid<o) red[tid]+=red[tid+o]; __syncthreads(); }
  const float mu = red[0]*(1.0f/NHID); __syncthreads();
  float vs=0.f;
  #pragma unroll
  for (int j=0;j<3;j++){ float d=e[j]-mu; vs+=d*d; }
  red[tid]=vs; __syncthreads();
  for (int o=128;o>0;o>>=1){ if (tid<o) red[tid]+=red[tid+o]; __syncthreads(); }
  const float rstd = 1.0f/sqrtf(red[0]*(1.0f/NHID)+LN_EPS);
  #pragma unroll
  for (int j=0;j<3;j++){
    int d = tid + j*256;
    out[(size_t)token*NHID + d] = (e[j]-mu)*rstd*g[d] + bvec[d];
  }
}

// ---------------- weight prep: W[K][N] f32 -> Wt[N][K] f16 hi/lo, k-tiled (32) ----------------
__global__ __launch_bounds__(256) void wprep_kernel(
    const float* __restrict__ W0, const float* __restrict__ W1, const float* __restrict__ W2,
    const float* __restrict__ W3, const float* __restrict__ W4, const float* __restrict__ W5,
    _Float16* __restrict__ OH, _Float16* __restrict__ OL)
{
  const int z = blockIdx.z;
  const int K_ = (z==5)?NFF:NHID;
  const int N_ = (z==4)?NFF:NHID;
  const int tI = blockIdx.y, nI = blockIdx.x;
  if (tI*32 >= K_ || nI*64 >= N_) return;
  const float* W = (z==0)?W0:(z==1)?W1:(z==2)?W2:(z==3)?W3:(z==4)?W4:W5;
  const size_t off = (z<5) ? (size_t)z*589824 : (size_t)4718592;
  __shared__ float T[32][66];
  const int tid = threadIdx.x;
  {
    const int kk = tid>>3, n8 = (tid&7)*8;
    const float* src = W + (size_t)(tI*32+kk)*N_ + nI*64 + n8;
    float4 v0 = *(const float4*)src;
    float4 v1 = *(const float4*)(src+4);
    T[kk][n8+0]=v0.x; T[kk][n8+1]=v0.y; T[kk][n8+2]=v0.z; T[kk][n8+3]=v0.w;
    T[kk][n8+4]=v1.x; T[kk][n8+5]=v1.y; T[kk][n8+6]=v1.z; T[kk][n8+7]=v1.w;
  }
  __syncthreads();
  const int n = tid>>2, c = tid&3;
  h8 hv, lv;
  #pragma unroll
  for (int j=0;j<8;j++){
    float x = T[c*8+j][n];
    _Float16 h = (_Float16)x;
    hv[j] = h;
    lv[j] = (_Float16)(x - (float)h);
  }
  _Float16* drow = OH + off + ((size_t)tI*N_ + (size_t)nI*64 + n)*32 + ((c ^ (n&3))*8);
  *(h8*)drow = hv;
  *(h8*)(OL + (drow - OH)) = lv;
}

// ---------------- split-f16 MFMA GEMM ----------------
// EPI: 0=f32 out, 1=exact GELU f32, 2=+res f32, 3=f16 hi/lo dual out
template<int EPI, int BN>
__global__ __launch_bounds__(256,2) void gemm_mfma(
    const float* __restrict__ A, const _Float16* __restrict__ WH, const _Float16* __restrict__ WL,
    const float* __restrict__ bias, const float* __restrict__ res, float* __restrict__ outp,
    _Float16* __restrict__ outh, _Float16* __restrict__ outl, int M, int N, int K)
{
  constexpr int NF = BN/32;
  __shared__ __align__(16) _Float16 Ah[128*32];
  __shared__ __align__(16) _Float16 Al[128*32];
  __shared__ __align__(16) _Float16 Bh[BN*32];
  __shared__ __align__(16) _Float16 Bl[BN*32];
  const int tid = threadIdx.x;
  const int w = tid>>6, l = tid&63;
  const int wm = w>>1, wn = w&1, lr = l&15, lc = l>>4;
  const int bm = blockIdx.y*128, bn = blockIdx.x*BN;
  const int T = K>>5;
  f4 acc[4][NF] = {};

  const int sr = tid>>1, sk = (tid&1)<<4;
  const float* aptr = A + (size_t)(bm+sr)*K + sk;
  _Float16* arH = Ah + sr*32;
  _Float16* arL = Al + sr*32;
  const int c0 = sk>>3;
  const int p0 = ((c0  ) ^ (sr&3))<<3;
  const int p1 = ((c0+1) ^ (sr&3))<<3;
  const int fsw = (lc ^ (lr&3))<<3;
  const int aBase = (wm*64 + lr)*32 + fsw;
  const int bBase = (wn*(BN/2) + lr)*32 + fsw;

  float4 ga0, ga1, ga2, ga3;
  uint4 gb0h = {}, gb0l = {}, gb1h = {}, gb1l = {};

  auto loadg = [&](int t){
    const float* ap = aptr + t*32;
    ga0 = *(const float4*)(ap);
    ga1 = *(const float4*)(ap+4);
    ga2 = *(const float4*)(ap+8);
    ga3 = *(const float4*)(ap+12);
    const uint4* bsH = (const uint4*)(WH + ((size_t)t*N + bn)*32);
    const uint4* bsL = (const uint4*)(WL + ((size_t)t*N + bn)*32);
    gb0h = bsH[tid]; gb0l = bsL[tid];
    if (NF==4){ gb1h = bsH[tid+256]; gb1l = bsL[tid+256]; }
  };
  loadg(0);

  for (int t=0; t<T; ++t){
    float xs[16] = {ga0.x,ga0.y,ga0.z,ga0.w, ga1.x,ga1.y,ga1.z,ga1.w,
                    ga2.x,ga2.y,ga2.z,ga2.w, ga3.x,ga3.y,ga3.z,ga3.w};
    h8 hv0, hv1, lv0, lv1;
    #pragma unroll
    for (int j=0;j<8;j++){
      _Float16 h0 = (_Float16)xs[j];
      hv0[j] = h0; lv0[j] = (_Float16)(xs[j] - (float)h0);
      _Float16 h1 = (_Float16)xs[8+j];
      hv1[j] = h1; lv1[j] = (_Float16)(xs[8+j] - (float)h1);
    }
    __syncthreads();
    *(h8*)(arH+p0) = hv0; *(h8*)(arH+p1) = hv1;
    *(h8*)(arL+p0) = lv0; *(h8*)(arL+p1) = lv1;
    ((uint4*)Bh)[tid] = gb0h; ((uint4*)Bl)[tid] = gb0l;
    if (NF==4){ ((uint4*)Bh)[tid+256] = gb1h; ((uint4*)Bl)[tid+256] = gb1l; }
    __syncthreads();
    if (t+1 < T) loadg(t+1);

    h8 ahv[4], alv[4];
    #pragma unroll
    for (int mf=0; mf<4; ++mf){
      ahv[mf] = *(const h8*)(Ah + aBase + mf*512);
      alv[mf] = *(const h8*)(Al + aBase + mf*512);
    }
    #pragma unroll
    for (int nf=0; nf<NF; ++nf){
      h8 bhv = *(const h8*)(Bh + bBase + nf*512);
      h8 blv = *(const h8*)(Bl + bBase + nf*512);
      #pragma unroll
      for (int mf=0; mf<4; ++mf){
        acc[mf][nf] = __builtin_amdgcn_mfma_f32_16x16x32_f16(ahv[mf], bhv, acc[mf][nf], 0,0,0);
        acc[mf][nf] = __builtin_amdgcn_mfma_f32_16x16x32_f16(alv[mf], bhv, acc[mf][nf], 0,0,0);
        acc[mf][nf] = __builtin_amdgcn_mfma_f32_16x16x32_f16(ahv[mf], blv, acc[mf][nf], 0,0,0);
      }
    }
  }
  #pragma unroll
  for (int nf=0; nf<NF; ++nf){
    const int n = bn + wn*(BN/2) + nf*16 + lr;
    const float bb = bias[n];
    #pragma unroll
    for (int mf=0; mf<4; ++mf){
      #pragma unroll
      for (int r=0; r<4; ++r){
        const int m = bm + wm*64 + mf*16 + lc*4 + r;
        float v = acc[mf][nf][r] + bb;
        if (EPI==1) v = 0.5f*v*(1.0f + erff(v*0.7071067811865476f));
        if (EPI==2) v += res[(size_t)m*N + n];
        if (EPI==3){
          _Float16 hh = (_Float16)v;
          outh[(size_t)m*N + n] = hh;
          outl[(size_t)m*N + n] = (_Float16)(v - (float)hh);
        } else {
          outp[(size_t)m*N + n] = v;
        }
      }
    }
  }
}

// ---------------- rel-position pre-gather -> f16 hi/lo [12][1024][64], row 1023 zeroed ----------------
__global__ __launch_bounds__(64) void relgather_kernel(
    const float* __restrict__ PKb, const float* __restrict__ PQb,
    _Float16* __restrict__ PKgh, _Float16* __restrict__ PKgl,
    _Float16* __restrict__ PQgh, _Float16* __restrict__ PQgl)
{
  const int r = blockIdx.x;       // 0..1023
  const int h = blockIdx.y;       // 0..11
  const int d = threadIdx.x;      // 0..63
  const size_t dst = ((size_t)h*1024 + r)*NDH + d;
  if (r >= 1023){ PKgh[dst]=(_Float16)0.f; PKgl[dst]=(_Float16)0.f;
                  PQgh[dst]=(_Float16)0.f; PQgl[dst]=(_Float16)0.f; return; }
  const int rel = r - 511;
  const int sg = (rel>0) - (rel<0);
  const float ap = (rel<128 && rel>-128) ? 127.0f : fabsf((float)rel);
  int bucket;
  if (ap <= 128.0f) bucket = rel;
  else bucket = (int)((ceilf(logf(ap*(1.0f/128.0f))/1.3843393f*127.0f)+128.0f)*(float)sg);
  const int idx = min(max(bucket+256,0),511);
  const size_t src = (size_t)idx*NHID + h*NDH + d;
  const float v1 = PKb[src], v2 = PQb[src];
  const _Float16 h1 = (_Float16)v1, h2 = (_Float16)v2;
  PKgh[dst]=h1; PKgl[dst]=(_Float16)(v1-(float)h1);
  PQgh[dst]=h2; PQgl[dst]=(_Float16)(v2-(float)h2);
}

// ---------------- V transpose: f32 [token][768] -> f16 hi/lo [bh][64][512] ----------------
__global__ __launch_bounds__(256) void vtrans_kernel(
    const float* __restrict__ V, _Float16* __restrict__ Vth, _Float16* __restrict__ Vtl)
{
  __shared__ float T[64][68];
  const int tid = threadIdx.x;
  const int k0 = blockIdx.x*64, h = blockIdx.y, b = blockIdx.z;
  const int bh = b*NHEAD + h;
  for (int i=tid; i<1024; i+=256){
    const int row = i>>4, c = i&15;
    *(float4*)&T[row][c*4] = *(const float4*)&V[(size_t)(b*NS + k0 + row)*NHID + h*NDH + c*4];
  }
  __syncthreads();
  for (int i=tid; i<512; i+=256){
    const int d = i>>3, kc = i&7;
    h8 hv, lv;
    #pragma unroll
    for (int j=0;j<8;++j){
      float x = T[kc*8+j][d];
      _Float16 hh = (_Float16)x;
      hv[j] = hh; lv[j] = (_Float16)(x - (float)hh);
    }
    const size_t dst = ((size_t)bh*NDH + d)*NS + k0 + kc*8;
    *(h8*)&Vth[dst] = hv;
    *(h8*)&Vtl[dst] = lv;
  }
}

// ---------------- banded positional matmul ----------------
// SGN=+1: out[bh,row,j] = X[row].P[row + j]        (Cq: c2p(q,k)=Cq[q][511-k])
// SGN=-1: out[bh,row,j] = X[row].P[511 - row + j]  (Cp: p2c(q,k)=Cp[k][q])
template<int SGN>
__global__ __launch_bounds__(256) void cband_kernel(
    const _Float16* __restrict__ Xh, const _Float16* __restrict__ Xl,
    const _Float16* __restrict__ Ph, const _Float16* __restrict__ Pl,
    _Float16* __restrict__ outC)
{
  __shared__ _Float16 Xsh[2048], Xsl[2048];
  __shared__ _Float16 Psh[2048], Psl[2048];
  __shared__ _Float16 Of[32*520];
  const int tid = threadIdx.x;
  const int row0 = blockIdx.x*32, h = blockIdx.y, b = blockIdx.z;
  const int bh = b*NHEAD + h;
  const int w = tid>>6, l = tid&63, lr = l&15, lc = l>>4;
  const int fsw = (lc ^ (lr&3))<<3;
  const int mf = w&1, nf = w>>1;
  {
    const int row = tid>>3, pl = (tid>>2)&1, c = tid&3;
    const size_t src = (size_t)(b*NS + row0 + row)*NHID + h*NDH + pl*32 + c*8;
    const int dst = pl*1024 + row*32 + ((c ^ (row&3))<<3);
    *(h8*)&Xsh[dst] = *(const h8*)&Xh[src];
    *(h8*)&Xsl[dst] = *(const h8*)&Xl[src];
  }
  __syncthreads();
  h8 xah[2], xal[2];
  #pragma unroll
  for (int pl=0; pl<2; ++pl){
    xah[pl] = *(const h8*)&Xsh[pl*1024 + (mf*16+lr)*32 + fsw];
    xal[pl] = *(const h8*)&Xsl[pl*1024 + (mf*16+lr)*32 + fsw];
  }
  const int rbase = (SGN>0) ? row0 : (480 - row0);
  for (int rt=0; rt<17; ++rt){
    __syncthreads();
    {
      const int rrow = tid>>3, pl = (tid>>2)&1, c = tid&3;
      const size_t src = ((size_t)h*1024 + rbase + rt*32 + rrow)*NDH + pl*32 + c*8;
      const int dst = pl*1024 + rrow*32 + ((c ^ (rrow&3))<<3);
      *(h8*)&Psh[dst] = *(const h8*)&Ph[src];
      *(h8*)&Psl[dst] = *(const h8*)&Pl[src];
    }
    __syncthreads();
    f4 cacc = {0.f,0.f,0.f,0.f};
    #pragma unroll
    for (int pl=0; pl<2; ++pl){
      h8 pbh = *(const h8*)&Psh[pl*1024 + (nf*16+lr)*32 + fsw];
      h8 pbl = *(const h8*)&Psl[pl*1024 + (nf*16+lr)*32 + fsw];
      cacc = __builtin_amdgcn_mfma_f32_16x16x32_f16(xah[pl], pbh, cacc, 0,0,0);
      cacc = __builtin_amdgcn_mfma_f32_16x16x32_f16(xal[pl], pbh, cacc, 0,0,0);
      cacc = __builtin_amdgcn_mfma_f32_16x16x32_f16(xah[pl], pbl, cacc, 0,0,0);
    }
    const int rl = rt*32 + nf*16 + lr;
    #pragma unroll
    for (int r=0; r<4; ++r){
      const int q = mf*16 + lc*4 + r;
      const int j = (SGN>0) ? (rl - q) : (rl + q - 31);
      if (j >= 0 && j < NS) Of[q*520 + j] = (_Float16)cacc[r];
    }
  }
  __syncthreads();
  for (int i=tid; i<2048; i+=256){
    const int row = i>>6, cc = i&63;
    *(h8*)&outC[((size_t)bh*NS + row0 + row)*NS + cc*8] = *(const h8*)&Of[row*520 + cc*8];
  }
}

// ---------------- MFMA flash disentangled attention ----------------
// block = (q-tile 32, h, b); S = (QK^T + Cq[q][511-k] + Cp[k][q]) * SC
__global__ __launch_bounds__(256) void attn_mfma(
    const _Float16* __restrict__ Qh, const _Float16* __restrict__ Ql,
    const _Float16* __restrict__ Kh, const _Float16* __restrict__ Kl,
    const _Float16* __restrict__ Vth, const _Float16* __restrict__ Vtl,
    const _Float16* __restrict__ Cq, const _Float16* __restrict__ Cp,
    const int* __restrict__ msk, float* __restrict__ Ctx)
{
  __shared__ _Float16 Qsh[2048], Qsl[2048];
  __shared__ _Float16 Ksh[4096], Ksl[4096];
  __shared__ _Float16 Vsh[4096], Vsl[4096];
  __shared__ _Float16 Psh[2048], Psl[2048];
  __shared__ float Ss[32][68];
  __shared__ float alphaS[32], invS[32];
  __shared__ int mqS[32], mkS[64];

  const int tid = threadIdx.x;
  const int qt = blockIdx.x, h = blockIdx.y, b = blockIdx.z;
  const int q0 = qt*32;
  const int bh = b*NHEAD + h;
  const int w = tid>>6, l = tid&63, lr = l&15, lc = l>>4;
  const int fsw = (lc ^ (lr&3))<<3;
  const int mf = w&1, ng = w>>1;

  {
    const int row = tid>>3, pl = (tid>>2)&1, c = tid&3;
    const size_t src = (size_t)(b*NS + q0 + row)*NHID + h*NDH + pl*32 + c*8;
    const int dst = pl*1024 + row*32 + ((c ^ (row&3))<<3);
    *(h8*)&Qsh[dst] = *(const h8*)&Qh[src];
    *(h8*)&Qsl[dst] = *(const h8*)&Ql[src];
  }
  if (tid < 32) mqS[tid] = msk[b*NS + q0 + tid];
  __syncthreads();

  h8 qah[2], qal[2];
  #pragma unroll
  for (int pl=0; pl<2; ++pl){
    qah[pl] = *(const h8*)&Qsh[pl*1024 + (mf*16+lr)*32 + fsw];
    qal[pl] = *(const h8*)&Qsl[pl*1024 + (mf*16+lr)*32 + fsw];
  }

  const int sq = tid>>3, sj = tid&7;
  float m_i = -3.4e38f, l_i = 0.f;
  f4 oacc[2] = {};

  for (int kt=0; kt<NS/64; ++kt){
    const int k0 = kt*64;
    __syncthreads();
    for (int i=tid; i<512; i+=256){
      const int row = i>>3, pl = (i>>2)&1, c = i&3;
      const size_t srcK = (size_t)(b*NS + k0 + row)*NHID + h*NDH + pl*32 + c*8;
      const int dstT = pl*2048 + row*32 + ((c ^ (row&3))<<3);
      *(h8*)&Ksh[dstT] = *(const h8*)&Kh[srcK];
      *(h8*)&Ksl[dstT] = *(const h8*)&Kl[srcK];
      const size_t srcV = ((size_t)bh*NDH + row)*NS + k0 + pl*32 + c*8;
      *(h8*)&Vsh[dstT] = *(const h8*)&Vth[srcV];
      *(h8*)&Vsl[dstT] = *(const h8*)&Vtl[srcV];
    }
    if (tid < 64) mkS[tid] = msk[b*NS + k0 + tid];
    __syncthreads();

    // QK^T + positional adds -> Ss
    #pragma unroll
    for (int nn=0; nn<2; ++nn){
      const int n = ng*2 + nn;
      f4 s = {0.f,0.f,0.f,0.f};
      #pragma unroll
      for (int pl=0; pl<2; ++pl){
        h8 kbh = *(const h8*)&Ksh[pl*2048 + (n*16+lr)*32 + fsw];
        h8 kbl = *(const h8*)&Ksl[pl*2048 + (n*16+lr)*32 + fsw];
        s = __builtin_amdgcn_mfma_f32_16x16x32_f16(qah[pl], kbh, s, 0,0,0);
        s = __builtin_amdgcn_mfma_f32_16x16x32_f16(qal[pl], kbh, s, 0,0,0);
        s = __builtin_amdgcn_mfma_f32_16x16x32_f16(qah[pl], kbl, s, 0,0,0);
      }
      const int kcol = n*16 + lr, kg = k0 + kcol;
      const int qbase = mf*16 + lc*4;
      const h4 cp4 = *(const h4*)&Cp[((size_t)bh*NS + kg)*NS + q0 + qbase];
      const int mk = mkS[kcol];
      #pragma unroll
      for (int r=0;r<4;++r){
        const int qloc = qbase + r;
        const float cq = (float)Cq[((size_t)bh*NS + q0 + qloc)*NS + (511 - kg)];
        const float val = (s[r] + cq + (float)cp4[r]) * 0.07216878364870322f;
        Ss[qloc][kcol] = (mk && mqS[qloc]) ? val : -3.4e38f;
      }
    }
    __syncthreads();

    // online softmax (8 lanes per q-row)
    const float4 sp0 = *(const float4*)&Ss[sq][sj*8];
    const float4 sp1 = *(const float4*)&Ss[sq][sj*8+4];
    float tm = fmaxf(fmaxf(fmaxf(sp0.x,sp0.y),fmaxf(sp0.z,sp0.w)),
                     fmaxf(fmaxf(sp1.x,sp1.y),fmaxf(sp1.z,sp1.w)));
    tm = fmaxf(tm, __shfl_xor(tm,1,8));
    tm = fmaxf(tm, __shfl_xor(tm,2,8));
    tm = fmaxf(tm, __shfl_xor(tm,4,8));
    const float m_new = fmaxf(m_i, tm);
    const float alpha = expf(m_i - m_new);
    float pv[8];
    pv[0]=expf(sp0.x-m_new); pv[1]=expf(sp0.y-m_new); pv[2]=expf(sp0.z-m_new); pv[3]=expf(sp0.w-m_new);
    pv[4]=expf(sp1.x-m_new); pv[5]=expf(sp1.y-m_new); pv[6]=expf(sp1.z-m_new); pv[7]=expf(sp1.w-m_new);
    float ts = pv[0]+pv[1]+pv[2]+pv[3]+pv[4]+pv[5]+pv[6]+pv[7];
    ts += __shfl_xor(ts,1,8);
    ts += __shfl_xor(ts,2,8);
    ts += __shfl_xor(ts,4,8);
    l_i = l_i*alpha + ts;
    m_i = m_new;
    h8 phv, plv;
    #pragma unroll
    for (int j=0;j<8;++j){
      _Float16 hh = (_Float16)pv[j];
      phv[j] = hh; plv[j] = (_Float16)(pv[j]-(float)hh);
    }
    const int pdst = (sj>>2)*1024 + sq*32 + ((((sj&3)) ^ (sq&3))<<3);
    *(h8*)&Psh[pdst] = phv;
    *(h8*)&Psl[pdst] = plv;
    if (sj==0) alphaS[sq] = alpha;
    __syncthreads();

    // PV accumulate
    float ar[4];
    #pragma unroll
    for (int r=0;r<4;++r) ar[r] = alphaS[mf*16 + lc*4 + r];
    #pragma unroll
    for (int nn=0;nn<2;++nn)
      #pragma unroll
      for (int r=0;r<4;++r) oacc[nn][r] *= ar[r];
    #pragma unroll
    for (int pl=0;pl<2;++pl){
      h8 pah = *(const h8*)&Psh[pl*1024 + (mf*16+lr)*32 + fsw];
      h8 pal = *(const h8*)&Psl[pl*1024 + (mf*16+lr)*32 + fsw];
      #pragma unroll
      for (int nn=0;nn<2;++nn){
        const int dn = ng*32 + nn*16 + lr;
        h8 vbh = *(const h8*)&Vsh[pl*2048 + dn*32 + fsw];
        h8 vbl = *(const h8*)&Vsl[pl*2048 + dn*32 + fsw];
        oacc[nn] = __builtin_amdgcn_mfma_f32_16x16x32_f16(pah, vbh, oacc[nn], 0,0,0);
        oacc[nn] = __builtin_amdgcn_mfma_f32_16x16x32_f16(pal, vbh, oacc[nn], 0,0,0);
        oacc[nn] = __builtin_amdgcn_mfma_f32_16x16x32_f16(pah, vbl, oacc[nn], 0,0,0);
      }
    }
  }

  const float inv = (l_i > 0.f && m_i > -1e30f && mqS[sq]) ? 1.0f/l_i : 0.f;
  if (sj==0) invS[sq] = inv;
  __syncthreads();
  #pragma unroll
  for (int nn=0;nn<2;++nn){
    #pragma unroll
    for (int r=0;r<4;++r){
      const int qloc = mf*16 + lc*4 + r;
      const int d = ng*32 + nn*16 + lr;
      Ctx[(size_t)(b*NS + q0 + qloc)*NHID + h*NDH + d] = oacc[nn][r] * invS[qloc];
    }
  }
}

extern "C" void kernel_launch(void* const* d_in, const int* in_sizes, int n_in,
                              void* d_out, int out_size, void* d_ws, size_t ws_size,
                              hipStream_t stream)
{
  const float* word_emb=(const float*)d_in[0];
  const float* pos_emb =(const float*)d_in[1];
  const float* emb_g   =(const float*)d_in[2];
  const float* emb_b   =(const float*)d_in[3];
  const float* rel_emb =(const float*)d_in[4];
  const float* Wq=(const float*)d_in[5];  const float* bq=(const float*)d_in[6];
  const float* Wk=(const float*)d_in[7];  const float* bk=(const float*)d_in[8];
  const float* Wv=(const float*)d_in[9];  const float* bvv=(const float*)d_in[10];
  const float* Wo=(const float*)d_in[11]; const float* bo=(const float*)d_in[12];
  const float* g1=(const float*)d_in[13]; const float* b1=(const float*)d_in[14];
  const float* Wi=(const float*)d_in[15]; const float* bi=(const float*)d_in[16];
  const float* Wo2=(const float*)d_in[17];const float* bo2=(const float*)d_in[18];
  const float* g2=(const float*)d_in[19]; const float* b2=(const float*)d_in[20];
  const int* ids  =(const int*)d_in[21];
  const int* amask=(const int*)d_in[22];

  char* p = (char*)d_ws;
  auto alloc = [&](size_t bytes)->char*{ char* r = p; p += (bytes + 255) & ~(size_t)255; return r; };
  float* Hb  = (float*)alloc((size_t)NTOK*NHID*4);
  float* H1  = (float*)alloc((size_t)NTOK*NHID*4);
  float* Xb  = (float*)alloc((size_t)NTOK*NHID*4);
  float* FFb = (float*)alloc((size_t)NTOK*NFF*4);
  float* Ctxb= (float*)alloc((size_t)NTOK*NHID*4);
  float* Vb  = (float*)alloc((size_t)NTOK*NHID*4);
  _Float16* Qhb = (_Float16*)alloc((size_t)NTOK*NHID*2);
  _Float16* Qlb = (_Float16*)alloc((size_t)NTOK*NHID*2);
  _Float16* Khb = (_Float16*)alloc((size_t)NTOK*NHID*2);
  _Float16* Klb = (_Float16*)alloc((size_t)NTOK*NHID*2);
  _Float16* Vth = (_Float16*)alloc((size_t)NTOK*NHID*2);
  _Float16* Vtl = (_Float16*)alloc((size_t)NTOK*NHID*2);
  float* PKb = (float*)alloc((size_t)512*NHID*4);
  float* PQb = (float*)alloc((size_t)512*NHID*4);
  _Float16* PKgh = (_Float16*)alloc((size_t)NHEAD*1024*NDH*2);
  _Float16* PKgl = (_Float16*)alloc((size_t)NHEAD*1024*NDH*2);
  _Float16* PQgh = (_Float16*)alloc((size_t)NHEAD*1024*NDH*2);
  _Float16* PQgl = (_Float16*)alloc((size_t)NHEAD*1024*NDH*2);
  _Float16* CqB = (_Float16*)alloc((size_t)NB*NHEAD*NS*NS*2);
  _Float16* CpB = (_Float16*)alloc((size_t)NB*NHEAD*NS*NS*2);
  _Float16* WtH = (_Float16*)alloc((size_t)7077888*2);
  _Float16* WtL = (_Float16*)alloc((size_t)7077888*2);

  const size_t WO[6] = {0, 589824, 1179648, 1769472, 2359296, 4718592};

  dim3 blk(256);
  dim3 gRel(1024, NHEAD);
  dim3 gAttn(NS/32, NHEAD, NB);
  dim3 gBand(NS/32, NHEAD, NB);
  dim3 gVt(NS/64, NHEAD, NB);
  dim3 gPrep(48, 96, 6);
  dim3 gSmall(12, 4);
  dim3 gProj(12, 32);
  dim3 gFF1(24, 32);

  emb_kernel<<<NTOK,blk,0,stream>>>(word_emb,pos_emb,emb_g,emb_b,ids,amask,Hb);

  for (int l=0; l<NL; l++){
    const float *Wq_l=Wq+(size_t)l*NHID*NHID, *bq_l=bq+(size_t)l*NHID;
    const float *Wk_l=Wk+(size_t)l*NHID*NHID, *bk_l=bk+(size_t)l*NHID;
    const float *Wv_l=Wv+(size_t)l*NHID*NHID, *bv_l=bvv+(size_t)l*NHID;
    const float *Wo_l=Wo+(size_t)l*NHID*NHID, *bo_l=bo+(size_t)l*NHID;
    const float *g1_l=g1+(size_t)l*NHID, *b1_l=b1+(size_t)l*NHID;
    const float *Wi_l=Wi+(size_t)l*NHID*NFF, *bi_l=bi+(size_t)l*NFF;
    const float *Wo2_l=Wo2+(size_t)l*NFF*NHID, *bo2_l=bo2+(size_t)l*NHID;
    const float *g2_l=g2+(size_t)l*NHID, *b2_l=b2+(size_t)l*NHID;

    wprep_kernel<<<gPrep,blk,0,stream>>>(Wq_l,Wk_l,Wv_l,Wo_l,Wi_l,Wo2_l,WtH,WtL);

    // relative position projections + gather/convert
    gemm_mfma<0,64><<<gSmall,blk,0,stream>>>(rel_emb, WtH+WO[1], WtL+WO[1], bk_l, nullptr, PKb, nullptr,nullptr, 512,NHID,NHID);
    gemm_mfma<0,64><<<gSmall,blk,0,stream>>>(rel_emb, WtH+WO[0], WtL+WO[0], bq_l, nullptr, PQb, nullptr,nullptr, 512,NHID,NHID);
    relgather_kernel<<<gRel,dim3(64),0,stream>>>(PKb, PQb, PKgh, PKgl, PQgh, PQgl);
    // Q,K (f16 hi/lo), V (f32 -> transposed f16 hi/lo)
    gemm_mfma<3,64><<<gProj,blk,0,stream>>>(Hb, WtH+WO[0], WtL+WO[0], bq_l, nullptr, nullptr, Qhb, Qlb, NTOK,NHID,NHID);
    gemm_mfma<3,64><<<gProj,blk,0,stream>>>(Hb, WtH+WO[1], WtL+WO[1], bk_l, nullptr, nullptr, Khb, Klb, NTOK,NHID,NHID);
    gemm_mfma<0,64><<<gProj,blk,0,stream>>>(Hb, WtH+WO[2], WtL+WO[2], bv_l, nullptr, Vb, nullptr,nullptr, NTOK,NHID,NHID);
    vtrans_kernel<<<gVt,blk,0,stream>>>(Vb, Vth, Vtl);
    // banded positional score tables
    cband_kernel<1><<<gBand,blk,0,stream>>>(Qhb, Qlb, PKgh, PKgl, CqB);
    cband_kernel<-1><<<gBand,blk,0,stream>>>(Khb, Klb, PQgh, PQgl, CpB);
    // attention
    attn_mfma<<<gAttn,blk,0,stream>>>(Qhb,Qlb,Khb,Klb,Vth,Vtl,CqB,CpB,amask,Ctxb);
    // output proj + residual, LN1
    gemm_mfma<2,64><<<gProj,blk,0,stream>>>(Ctxb, WtH+WO[3], WtL+WO[3], bo_l, Hb, Xb, nullptr,nullptr, NTOK,NHID,NHID);
    ln_kernel<<<NTOK,blk,0,stream>>>(Xb, g1_l, b1_l, H1);
    // FFN
    gemm_mfma<1,128><<<gFF1,blk,0,stream>>>(H1, WtH+WO[4], WtL+WO[4], bi_l, nullptr, FFb, nullptr,nullptr, NTOK,NFF,NHID);
    gemm_mfma<2,64><<<gProj,blk,0,stream>>>(FFb, WtH+WO[5], WtL+WO[5], bo2_l, H1, Xb, nullptr,nullptr, NTOK,NHID,NFF);
    float* dst = (l==NL-1) ? (float*)d_out : Hb;
    ln_kernel<<<NTOK,blk,0,stream>>>(Xb, g2_l, b2_l, dst);
  }
}

// Round 3
// 7173.273 us; speedup vs baseline: 2.2061x; 1.0291x over previous
//
#include <hip/hip_runtime.h>
#include <hip/hip_bf16.h>
#include <cmath>

#define NB 8
#define NS 512
#define NHID 768
#define NHEAD 12
#define NL 12
#define NDH 64
#define NFF 3072
#define NTOK (NB*NS)
#define LN_EPS 1e-7f

typedef _Float16 h8 __attribute__((ext_vector_type(8)));
typedef _Float16 h4 __attribute__((ext_vector_type(4)));
typedef float f4 __attribute__((ext_vector_type(4)));

// async 16B global->LDS (LDS dest: wave-uniform base + lane*16)
#define GL(dst, src) __builtin_amdgcn_global_load_lds( \
    (const __attribute__((address_space(1))) void*)(src), \
    (__attribute__((address_space(3))) void*)(dst), 16, 0, 0)

// ---------------- embedding: gather + LN + mask, f32 + f16 hi/lo planes ----------------
__global__ __launch_bounds__(256) void emb_kernel(
    const float* __restrict__ we, const float* __restrict__ pe,
    const float* __restrict__ g, const float* __restrict__ bvec,
    const int* __restrict__ ids, const int* __restrict__ msk, float* __restrict__ out,
    _Float16* __restrict__ oh, _Float16* __restrict__ ol)
{
  const int token = blockIdx.x, tid = threadIdx.x;
  const int s = token & (NS-1);
  __shared__ float red[256];
  const int id = ids[token];
  const float* wp = we + (size_t)id*NHID;
  const float* pp = pe + (size_t)s*NHID;
  float e[3]; float sum = 0.f;
  #pragma unroll
  for (int j=0;j<3;j++){ int d = tid + j*256; e[j] = wp[d] + pp[d]; sum += e[j]; }
  red[tid]=sum; __syncthreads();
  for (int o=128;o>0;o>>=1){ if (tid<o) red[tid]+=red[tid+o]; __syncthreads(); }
  const float mu = red[0]*(1.0f/NHID); __syncthreads();
  float vs=0.f;
  #pragma unroll
  for (int j=0;j<3;j++){ float d=e[j]-mu; vs += d*d; }
  red[tid]=vs; __syncthreads();
  for (int o=128;o>0;o>>=1){ if (tid<o) red[tid]+=red[tid+o]; __syncthreads(); }
  const float rstd = 1.0f/sqrtf(red[0]*(1.0f/NHID)+LN_EPS);
  const float mf = (float)msk[token];
  #pragma unroll
  for (int j=0;j<3;j++){
    int d = tid + j*256;
    float v = ((e[j]-mu)*rstd*g[d] + bvec[d])*mf;
    out[(size_t)token*NHID + d] = v;
    _Float16 hh = (_Float16)v;
    oh[(size_t)token*NHID + d] = hh;
    ol[(size_t)token*NHID + d] = (_Float16)(v - (float)hh);
  }
}

// ---------------- LayerNorm: f32 out + f16 hi/lo planes ----------------
__global__ __launch_bounds__(256) void ln_kernel(
    const float* __restrict__ X, const float* __restrict__ g, const float* __restrict__ bvec,
    float* __restrict__ out, _Float16* __restrict__ oh, _Float16* __restrict__ ol)
{
  const int token = blockIdx.x, tid = threadIdx.x;
  __shared__ float red[256];
  const float* x = X + (size_t)token*NHID;
  float e[3]; float sum=0.f;
  #pragma unroll
  for (int j=0;j<3;j++){ e[j]=x[tid+j*256]; sum+=e[j]; }
  red[tid]=sum; __syncthreads();
  for (int o=128;o>0;o>>=1){ if (tid<o) red[tid]+=red[tid+o]; __syncthreads(); }
  const float mu = red[0]*(1.0f/NHID); __syncthreads();
  float vs=0.f;
  #pragma unroll
  for (int j=0;j<3;j++){ float d=e[j]-mu; vs+=d*d; }
  red[tid]=vs; __syncthreads();
  for (int o=128;o>0;o>>=1){ if (tid<o) red[tid]+=red[tid+o]; __syncthreads(); }
  const float rstd = 1.0f/sqrtf(red[0]*(1.0f/NHID)+LN_EPS);
  #pragma unroll
  for (int j=0;j<3;j++){
    int d = tid + j*256;
    float v = (e[j]-mu)*rstd*g[d] + bvec[d];
    out[(size_t)token*NHID + d] = v;
    _Float16 hh = (_Float16)v;
    oh[(size_t)token*NHID + d] = hh;
    ol[(size_t)token*NHID + d] = (_Float16)(v - (float)hh);
  }
}

// ---------------- f32 -> f16 hi/lo planes (for rel_emb, once) ----------------
__global__ __launch_bounds__(256) void planes_kernel(
    const float* __restrict__ X, _Float16* __restrict__ oh, _Float16* __restrict__ ol, int n8)
{
  const int i = blockIdx.x*256 + threadIdx.x;
  if (i >= n8) return;
  const float4 v0 = ((const float4*)X)[i*2];
  const float4 v1 = ((const float4*)X)[i*2+1];
  const float xs[8] = {v0.x,v0.y,v0.z,v0.w,v1.x,v1.y,v1.z,v1.w};
  h8 hv, lv;
  #pragma unroll
  for (int j=0;j<8;j++){
    _Float16 hh = (_Float16)xs[j];
    hv[j]=hh; lv[j]=(_Float16)(xs[j]-(float)hh);
  }
  *(h8*)&oh[(size_t)i*8] = hv;
  *(h8*)&ol[(size_t)i*8] = lv;
}

// ---------------- weight prep: W[K][N] f32 -> k-tiled f16 hi/lo with sw(n) chunk swizzle ----------------
// mem[(t*N + n)*32 + (c ^ sw(n))*8 + j] = W[t*32 + c*8 + j][n], sw(n)=(n&3)^((n>>2)&3)
__global__ __launch_bounds__(256) void wprep_kernel(
    const float* __restrict__ W0, const float* __restrict__ W1, const float* __restrict__ W2,
    const float* __restrict__ W3, const float* __restrict__ W4, const float* __restrict__ W5,
    _Float16* __restrict__ OH, _Float16* __restrict__ OL)
{
  const int z = blockIdx.z;
  const int K_ = (z==5)?NFF:NHID;
  const int N_ = (z==4)?NFF:NHID;
  const int tI = blockIdx.y, nI = blockIdx.x;
  if (tI*32 >= K_ || nI*64 >= N_) return;
  const float* W = (z==0)?W0:(z==1)?W1:(z==2)?W2:(z==3)?W3:(z==4)?W4:W5;
  const size_t off = (z<5) ? (size_t)z*589824 : (size_t)4718592;
  __shared__ float T[32][66];
  const int tid = threadIdx.x;
  {
    const int kk = tid>>3, n8 = (tid&7)*8;
    const float* src = W + (size_t)(tI*32+kk)*N_ + nI*64 + n8;
    float4 v0 = *(const float4*)src;
    float4 v1 = *(const float4*)(src+4);
    T[kk][n8+0]=v0.x; T[kk][n8+1]=v0.y; T[kk][n8+2]=v0.z; T[kk][n8+3]=v0.w;
    T[kk][n8+4]=v1.x; T[kk][n8+5]=v1.y; T[kk][n8+6]=v1.z; T[kk][n8+7]=v1.w;
  }
  __syncthreads();
  const int n = tid>>2, c = tid&3;
  h8 hv, lv;
  #pragma unroll
  for (int j=0;j<8;j++){
    float x = T[c*8+j][n];
    _Float16 h = (_Float16)x;
    hv[j] = h;
    lv[j] = (_Float16)(x - (float)h);
  }
  const int sw = (n&3) ^ ((n>>2)&3);
  _Float16* drow = OH + off + ((size_t)tI*N_ + (size_t)nI*64 + n)*32 + ((c ^ sw)*8);
  *(h8*)drow = hv;
  *(h8*)(OL + (drow - OH)) = lv;
}

// ---------------- split-f16 MFMA GEMM v2: async gload_lds double-buffer ----------------
// A: f16 hi/lo planes [M][K] (unswizzled; swizzle baked into staging src addr)
// B: wprep layout (swizzle baked in memory; linear staging)
// EPI: 0=f32 out, 1=GELU -> f16 hi/lo, 2=+res f32, 3=f16 hi/lo
template<int EPI, int BN>
__global__ __launch_bounds__(256,2) void gemm2(
    const _Float16* __restrict__ Ah, const _Float16* __restrict__ Al,
    const _Float16* __restrict__ WH, const _Float16* __restrict__ WL,
    const float* __restrict__ bias, const float* __restrict__ res,
    float* __restrict__ outp, _Float16* __restrict__ outh, _Float16* __restrict__ outl,
    int M, int N, int K, int nbx)
{
  constexpr int NF = BN/32;
  constexpr int BH = BN*32;
  __shared__ __align__(16) _Float16 LAh[2*4096];
  __shared__ __align__(16) _Float16 LAl[2*4096];
  __shared__ __align__(16) _Float16 LBh[2*BH];
  __shared__ __align__(16) _Float16 LBl[2*BH];
  const int tid = threadIdx.x;
  const int w = tid>>6, l = tid&63;
  // bijective XCD remap (all grids are multiples of 8)
  const int orig = blockIdx.x;
  const int wg = (orig&7)*((int)gridDim.x>>3) + (orig>>3);
  const int bx = wg % nbx, by = wg / nbx;
  const int bm = by*128, bn = bx*BN;
  const int T = K>>5;

  const int lr = l&15, lc = l>>4;
  const int wm = w>>1, wn = w&1;
  const int fsw = ((lc ^ (lr&3) ^ ((lr>>2)&3))<<3);
  const int aBase = (wm*64 + lr)*32 + fsw;
  const int bBase = (wn*(BN/2) + lr)*32 + fsw;

  // staging: wave w covers A rows [w*32, w*32+32); lane l -> row w*32+(l>>2), chunk l&3 (x2 for +16 rows)
  const int rowA = (w<<5) + (l>>2);
  const int cA = l&3;
  const int swA = (rowA&3) ^ ((rowA>>2)&3);
  const _Float16* aSrcH = Ah + (size_t)(bm+rowA)*K + ((cA ^ swA)<<3);
  const _Float16* aSrcL = Al + (size_t)(bm+rowA)*K + ((cA ^ swA)<<3);
  const int a16K = 16*K;
  const size_t bLane = (size_t)(BN==64 ? w*512 : w*1024) + l*8;
  const _Float16* bSrcH = WH + (size_t)bn*32 + bLane;
  const _Float16* bSrcL = WL + (size_t)bn*32 + bLane;
  const size_t bStep = (size_t)N*32;
  const int bWOff = (BN==64) ? w*512 : w*1024;

  auto stage = [&](int b2){
    _Float16* dAh = LAh + b2*4096 + w*1024;
    _Float16* dAl = LAl + b2*4096 + w*1024;
    GL(dAh,     aSrcH); GL(dAh+512, aSrcH + a16K);
    GL(dAl,     aSrcL); GL(dAl+512, aSrcL + a16K);
    _Float16* dBh = LBh + b2*BH + bWOff;
    _Float16* dBl = LBl + b2*BH + bWOff;
    GL(dBh, bSrcH); GL(dBl, bSrcL);
    if (BN==128){ GL(dBh+512, bSrcH+512); GL(dBl+512, bSrcL+512); }
    aSrcH += 32; aSrcL += 32; bSrcH += bStep; bSrcL += bStep;
  };

  f4 acc[4][NF] = {};
  stage(0);
  asm volatile("s_waitcnt vmcnt(0)" ::: "memory");
  __syncthreads();
  int buf = 0;
  for (int t=0; t<T; ++t){
    if (t+1 < T) stage(buf^1);
    const _Float16* pAh = LAh + buf*4096;
    const _Float16* pAl = LAl + buf*4096;
    const _Float16* pBh = LBh + buf*BH;
    const _Float16* pBl = LBl + buf*BH;
    h8 ahv[4], alv[4];
    #pragma unroll
    for (int mf=0; mf<4; ++mf){
      ahv[mf] = *(const h8*)(pAh + aBase + mf*512);
      alv[mf] = *(const h8*)(pAl + aBase + mf*512);
    }
    #pragma unroll
    for (int nf=0; nf<NF; ++nf){
      h8 bhv = *(const h8*)(pBh + bBase + nf*512);
      h8 blv = *(const h8*)(pBl + bBase + nf*512);
      #pragma unroll
      for (int mf=0; mf<4; ++mf){
        acc[mf][nf] = __builtin_amdgcn_mfma_f32_16x16x32_f16(ahv[mf], bhv, acc[mf][nf], 0,0,0);
        acc[mf][nf] = __builtin_amdgcn_mfma_f32_16x16x32_f16(alv[mf], bhv, acc[mf][nf], 0,0,0);
        acc[mf][nf] = __builtin_amdgcn_mfma_f32_16x16x32_f16(ahv[mf], blv, acc[mf][nf], 0,0,0);
      }
    }
    asm volatile("s_waitcnt vmcnt(0)" ::: "memory");
    __syncthreads();
    buf ^= 1;
  }
  // epilogue: C/D layout col=lane&15, row=(lane>>4)*4+reg
  #pragma unroll
  for (int nf=0; nf<NF; ++nf){
    const int n = bn + wn*(BN/2) + nf*16 + lr;
    const float bb = bias[n];
    #pragma unroll
    for (int mf=0; mf<4; ++mf){
      #pragma unroll
      for (int r=0; r<4; ++r){
        const int m = bm + wm*64 + mf*16 + lc*4 + r;
        float v = acc[mf][nf][r] + bb;
        if (EPI==1){
          v = 0.5f*v*(1.0f + erff(v*0.7071067811865476f));
          _Float16 hh = (_Float16)v;
          outh[(size_t)m*N + n] = hh;
          outl[(size_t)m*N + n] = (_Float16)(v - (float)hh);
        } else if (EPI==3){
          _Float16 hh = (_Float16)v;
          outh[(size_t)m*N + n] = hh;
          outl[(size_t)m*N + n] = (_Float16)(v - (float)hh);
        } else {
          if (EPI==2) v += res[(size_t)m*N + n];
          outp[(size_t)m*N + n] = v;
        }
      }
    }
  }
}

// ---------------- rel-position pre-gather -> f16 hi/lo [12][1024][64], row 1023 zeroed ----------------
__global__ __launch_bounds__(64) void relgather_kernel(
    const float* __restrict__ PKb, const float* __restrict__ PQb,
    _Float16* __restrict__ PKgh, _Float16* __restrict__ PKgl,
    _Float16* __restrict__ PQgh, _Float16* __restrict__ PQgl)
{
  const int r = blockIdx.x;       // 0..1023
  const int h = blockIdx.y;       // 0..11
  const int d = threadIdx.x;      // 0..63
  const size_t dst = ((size_t)h*1024 + r)*NDH + d;
  if (r >= 1023){ PKgh[dst]=(_Float16)0.f; PKgl[dst]=(_Float16)0.f;
                  PQgh[dst]=(_Float16)0.f; PQgl[dst]=(_Float16)0.f; return; }
  const int rel = r - 511;
  const int sg = (rel>0) - (rel<0);
  const float ap = (rel<128 && rel>-128) ? 127.0f : fabsf((float)rel);
  int bucket;
  if (ap <= 128.0f) bucket = rel;
  else bucket = (int)((ceilf(logf(ap*(1.0f/128.0f))/1.3843393f*127.0f)+128.0f)*(float)sg);
  const int idx = min(max(bucket+256,0),511);
  const size_t src = (size_t)idx*NHID + h*NDH + d;
  const float v1 = PKb[src], v2 = PQb[src];
  const _Float16 h1 = (_Float16)v1, h2 = (_Float16)v2;
  PKgh[dst]=h1; PKgl[dst]=(_Float16)(v1-(float)h1);
  PQgh[dst]=h2; PQgl[dst]=(_Float16)(v2-(float)h2);
}

// ---------------- V transpose: f32 [token][768] -> f16 hi/lo [bh][64][512] ----------------
__global__ __launch_bounds__(256) void vtrans_kernel(
    const float* __restrict__ V, _Float16* __restrict__ Vth, _Float16* __restrict__ Vtl)
{
  __shared__ float T[64][68];
  const int tid = threadIdx.x;
  const int k0 = blockIdx.x*64, h = blockIdx.y, b = blockIdx.z;
  const int bh = b*NHEAD + h;
  for (int i=tid; i<1024; i+=256){
    const int row = i>>4, c = i&15;
    *(float4*)&T[row][c*4] = *(const float4*)&V[(size_t)(b*NS + k0 + row)*NHID + h*NDH + c*4];
  }
  __syncthreads();
  for (int i=tid; i<512; i+=256){
    const int d = i>>3, kc = i&7;
    h8 hv, lv;
    #pragma unroll
    for (int j=0;j<8;++j){
      float x = T[kc*8+j][d];
      _Float16 hh = (_Float16)x;
      hv[j] = hh; lv[j] = (_Float16)(x - (float)hh);
    }
    const size_t dst = ((size_t)bh*NDH + d)*NS + k0 + kc*8;
    *(h8*)&Vth[dst] = hv;
    *(h8*)&Vtl[dst] = lv;
  }
}

// ---------------- banded positional matmul ----------------
// SGN=+1: out[bh,row,j] = X[row].P[row + j]        (Cq: c2p(q,k)=Cq[q][511-k])
// SGN=-1: out[bh,row,j] = X[row].P[511 - row + j]  (Cp: p2c(q,k)=Cp[k][q])
template<int SGN>
__global__ __launch_bounds__(256) void cband_kernel(
    const _Float16* __restrict__ Xh, const _Float16* __restrict__ Xl,
    const _Float16* __restrict__ Ph, const _Float16* __restrict__ Pl,
    _Float16* __restrict__ outC)
{
  __shared__ _Float16 Xsh[2048], Xsl[2048];
  __shared__ _Float16 Psh[2048], Psl[2048];
  __shared__ _Float16 Of[32*520];
  const int tid = threadIdx.x;
  const int row0 = blockIdx.x*32, h = blockIdx.y, b = blockIdx.z;
  const int bh = b*NHEAD + h;
  const int w = tid>>6, l = tid&63, lr = l&15, lc = l>>4;
  const int fsw = (lc ^ (lr&3))<<3;
  const int mf = w&1, nf = w>>1;
  {
    const int row = tid>>3, pl = (tid>>2)&1, c = tid&3;
    const size_t src = (size_t)(b*NS + row0 + row)*NHID + h*NDH + pl*32 + c*8;
    const int dst = pl*1024 + row*32 + ((c ^ (row&3))<<3);
    *(h8*)&Xsh[dst] = *(const h8*)&Xh[src];
    *(h8*)&Xsl[dst] = *(const h8*)&Xl[src];
  }
  __syncthreads();
  h8 xah[2], xal[2];
  #pragma unroll
  for (int pl=0; pl<2; ++pl){
    xah[pl] = *(const h8*)&Xsh[pl*1024 + (mf*16+lr)*32 + fsw];
    xal[pl] = *(const h8*)&Xsl[pl*1024 + (mf*16+lr)*32 + fsw];
  }
  const int rbase = (SGN>0) ? row0 : (480 - row0);
  for (int rt=0; rt<17; ++rt){
    __syncthreads();
    {
      const int rrow = tid>>3, pl = (tid>>2)&1, c = tid&3;
      const size_t src = ((size_t)h*1024 + rbase + rt*32 + rrow)*NDH + pl*32 + c*8;
      const int dst = pl*1024 + rrow*32 + ((c ^ (rrow&3))<<3);
      *(h8*)&Psh[dst] = *(const h8*)&Ph[src];
      *(h8*)&Psl[dst] = *(const h8*)&Pl[src];
    }
    __syncthreads();
    f4 cacc = {0.f,0.f,0.f,0.f};
    #pragma unroll
    for (int pl=0; pl<2; ++pl){
      h8 pbh = *(const h8*)&Psh[pl*1024 + (nf*16+lr)*32 + fsw];
      h8 pbl = *(const h8*)&Psl[pl*1024 + (nf*16+lr)*32 + fsw];
      cacc = __builtin_amdgcn_mfma_f32_16x16x32_f16(xah[pl], pbh, cacc, 0,0,0);
      cacc = __builtin_amdgcn_mfma_f32_16x16x32_f16(xal[pl], pbh, cacc, 0,0,0);
      cacc = __builtin_amdgcn_mfma_f32_16x16x32_f16(xah[pl], pbl, cacc, 0,0,0);
    }
    const int rl = rt*32 + nf*16 + lr;
    #pragma unroll
    for (int r=0; r<4; ++r){
      const int q = mf*16 + lc*4 + r;
      const int j = (SGN>0) ? (rl - q) : (rl + q - 31);
      if (j >= 0 && j < NS) Of[q*520 + j] = (_Float16)cacc[r];
    }
  }
  __syncthreads();
  for (int i=tid; i<2048; i+=256){
    const int row = i>>6, cc = i&63;
    *(h8*)&outC[((size_t)bh*NS + row0 + row)*NS + cc*8] = *(const h8*)&Of[row*520 + cc*8];
  }
}

// ---------------- MFMA flash disentangled attention ----------------
__global__ __launch_bounds__(256) void attn_mfma(
    const _Float16* __restrict__ Qh, const _Float16* __restrict__ Ql,
    const _Float16* __restrict__ Kh, const _Float16* __restrict__ Kl,
    const _Float16* __restrict__ Vth, const _Float16* __restrict__ Vtl,
    const _Float16* __restrict__ Cq, const _Float16* __restrict__ Cp,
    const int* __restrict__ msk, _Float16* __restrict__ Ctxh, _Float16* __restrict__ Ctxl)
{
  __shared__ _Float16 Qsh[2048], Qsl[2048];
  __shared__ _Float16 Ksh[4096], Ksl[4096];
  __shared__ _Float16 Vsh[4096], Vsl[4096];
  __shared__ _Float16 Psh[2048], Psl[2048];
  __shared__ float Ss[32][68];
  __shared__ float alphaS[32], invS[32];
  __shared__ int mqS[32], mkS[64];

  const int tid = threadIdx.x;
  const int qt = blockIdx.x, h = blockIdx.y, b = blockIdx.z;
  const int q0 = qt*32;
  const int bh = b*NHEAD + h;
  const int w = tid>>6, l = tid&63, lr = l&15, lc = l>>4;
  const int fsw = (lc ^ (lr&3))<<3;
  const int mf = w&1, ng = w>>1;

  {
    const int row = tid>>3, pl = (tid>>2)&1, c = tid&3;
    const size_t src = (size_t)(b*NS + q0 + row)*NHID + h*NDH + pl*32 + c*8;
    const int dst = pl*1024 + row*32 + ((c ^ (row&3))<<3);
    *(h8*)&Qsh[dst] = *(const h8*)&Qh[src];
    *(h8*)&Qsl[dst] = *(const h8*)&Ql[src];
  }
  if (tid < 32) mqS[tid] = msk[b*NS + q0 + tid];
  __syncthreads();

  h8 qah[2], qal[2];
  #pragma unroll
  for (int pl=0; pl<2; ++pl){
    qah[pl] = *(const h8*)&Qsh[pl*1024 + (mf*16+lr)*32 + fsw];
    qal[pl] = *(const h8*)&Qsl[pl*1024 + (mf*16+lr)*32 + fsw];
  }

  const int sq = tid>>3, sj = tid&7;
  float m_i = -3.4e38f, l_i = 0.f;
  f4 oacc[2] = {};

  for (int kt=0; kt<NS/64; ++kt){
    const int k0 = kt*64;
    __syncthreads();
    for (int i=tid; i<512; i+=256){
      const int row = i>>3, pl = (i>>2)&1, c = i&3;
      const size_t srcK = (size_t)(b*NS + k0 + row)*NHID + h*NDH + pl*32 + c*8;
      const int dstT = pl*2048 + row*32 + ((c ^ (row&3))<<3);
      *(h8*)&Ksh[dstT] = *(const h8*)&Kh[srcK];
      *(h8*)&Ksl[dstT] = *(const h8*)&Kl[srcK];
      const size_t srcV = ((size_t)bh*NDH + row)*NS + k0 + pl*32 + c*8;
      *(h8*)&Vsh[dstT] = *(const h8*)&Vth[srcV];
      *(h8*)&Vsl[dstT] = *(const h8*)&Vtl[srcV];
    }
    if (tid < 64) mkS[tid] = msk[b*NS + k0 + tid];
    __syncthreads();

    #pragma unroll
    for (int nn=0; nn<2; ++nn){
      const int n = ng*2 + nn;
      f4 s = {0.f,0.f,0.f,0.f};
      #pragma unroll
      for (int pl=0; pl<2; ++pl){
        h8 kbh = *(const h8*)&Ksh[pl*2048 + (n*16+lr)*32 + fsw];
        h8 kbl = *(const h8*)&Ksl[pl*2048 + (n*16+lr)*32 + fsw];
        s = __builtin_amdgcn_mfma_f32_16x16x32_f16(qah[pl], kbh, s, 0,0,0);
        s = __builtin_amdgcn_mfma_f32_16x16x32_f16(qal[pl], kbh, s, 0,0,0);
        s = __builtin_amdgcn_mfma_f32_16x16x32_f16(qah[pl], kbl, s, 0,0,0);
      }
      const int kcol = n*16 + lr, kg = k0 + kcol;
      const int qbase = mf*16 + lc*4;
      const h4 cp4 = *(const h4*)&Cp[((size_t)bh*NS + kg)*NS + q0 + qbase];
      const int mk = mkS[kcol];
      #pragma unroll
      for (int r=0;r<4;++r){
        const int qloc = qbase + r;
        const float cq = (float)Cq[((size_t)bh*NS + q0 + qloc)*NS + (511 - kg)];
        const float val = (s[r] + cq + (float)cp4[r]) * 0.07216878364870322f;
        Ss[qloc][kcol] = (mk && mqS[qloc]) ? val : -3.4e38f;
      }
    }
    __syncthreads();

    const float4 sp0 = *(const float4*)&Ss[sq][sj*8];
    const float4 sp1 = *(const float4*)&Ss[sq][sj*8+4];
    float tm = fmaxf(fmaxf(fmaxf(sp0.x,sp0.y),fmaxf(sp0.z,sp0.w)),
                     fmaxf(fmaxf(sp1.x,sp1.y),fmaxf(sp1.z,sp1.w)));
    tm = fmaxf(tm, __shfl_xor(tm,1,8));
    tm = fmaxf(tm, __shfl_xor(tm,2,8));
    tm = fmaxf(tm, __shfl_xor(tm,4,8));
    const float m_new = fmaxf(m_i, tm);
    const float alpha = expf(m_i - m_new);
    float pv[8];
    pv[0]=expf(sp0.x-m_new); pv[1]=expf(sp0.y-m_new); pv[2]=expf(sp0.z-m_new); pv[3]=expf(sp0.w-m_new);
    pv[4]=expf(sp1.x-m_new); pv[5]=expf(sp1.y-m_new); pv[6]=expf(sp1.z-m_new); pv[7]=expf(sp1.w-m_new);
    float ts = pv[0]+pv[1]+pv[2]+pv[3]+pv[4]+pv[5]+pv[6]+pv[7];
    ts += __shfl_xor(ts,1,8);
    ts += __shfl_xor(ts,2,8);
    ts += __shfl_xor(ts,4,8);
    l_i = l_i*alpha + ts;
    m_i = m_new;
    h8 phv, plv;
    #pragma unroll
    for (int j=0;j<8;++j){
      _Float16 hh = (_Float16)pv[j];
      phv[j] = hh; plv[j] = (_Float16)(pv[j]-(float)hh);
    }
    const int pdst = (sj>>2)*1024 + sq*32 + ((((sj&3)) ^ (sq&3))<<3);
    *(h8*)&Psh[pdst] = phv;
    *(h8*)&Psl[pdst] = plv;
    if (sj==0) alphaS[sq] = alpha;
    __syncthreads();

    float ar[4];
    #pragma unroll
    for (int r=0;r<4;++r) ar[r] = alphaS[mf*16 + lc*4 + r];
    #pragma unroll
    for (int nn=0;nn<2;++nn)
      #pragma unroll
      for (int r=0;r<4;++r) oacc[nn][r] *= ar[r];
    #pragma unroll
    for (int pl=0;pl<2;++pl){
      h8 pah = *(const h8*)&Psh[pl*1024 + (mf*16+lr)*32 + fsw];
      h8 pal = *(const h8*)&Psl[pl*1024 + (mf*16+lr)*32 + fsw];
      #pragma unroll
      for (int nn=0;nn<2;++nn){
        const int dn = ng*32 + nn*16 + lr;
        h8 vbh = *(const h8*)&Vsh[pl*2048 + dn*32 + fsw];
        h8 vbl = *(const h8*)&Vsl[pl*2048 + dn*32 + fsw];
        oacc[nn] = __builtin_amdgcn_mfma_f32_16x16x32_f16(pah, vbh, oacc[nn], 0,0,0);
        oacc[nn] = __builtin_amdgcn_mfma_f32_16x16x32_f16(pal, vbh, oacc[nn], 0,0,0);
        oacc[nn] = __builtin_amdgcn_mfma_f32_16x16x32_f16(pah, vbl, oacc[nn], 0,0,0);
      }
    }
  }

  const float inv = (l_i > 0.f && m_i > -1e30f && mqS[sq]) ? 1.0f/l_i : 0.f;
  if (sj==0) invS[sq] = inv;
  __syncthreads();
  #pragma unroll
  for (int nn=0;nn<2;++nn){
    #pragma unroll
    for (int r=0;r<4;++r){
      const int qloc = mf*16 + lc*4 + r;
      const int d = ng*32 + nn*16 + lr;
      const float v = oacc[nn][r] * invS[qloc];
      const _Float16 hh = (_Float16)v;
      const size_t idx = (size_t)(b*NS + q0 + qloc)*NHID + h*NDH + d;
      Ctxh[idx] = hh;
      Ctxl[idx] = (_Float16)(v - (float)hh);
    }
  }
}

extern "C" void kernel_launch(void* const* d_in, const int* in_sizes, int n_in,
                              void* d_out, int out_size, void* d_ws, size_t ws_size,
                              hipStream_t stream)
{
  const float* word_emb=(const float*)d_in[0];
  const float* pos_emb =(const float*)d_in[1];
  const float* emb_g   =(const float*)d_in[2];
  const float* emb_b   =(const float*)d_in[3];
  const float* rel_emb =(const float*)d_in[4];
  const float* Wq=(const float*)d_in[5];  const float* bq=(const float*)d_in[6];
  const float* Wk=(const float*)d_in[7];  const float* bk=(const float*)d_in[8];
  const float* Wv=(const float*)d_in[9];  const float* bvv=(const float*)d_in[10];
  const float* Wo=(const float*)d_in[11]; const float* bo=(const float*)d_in[12];
  const float* g1=(const float*)d_in[13]; const float* b1=(const float*)d_in[14];
  const float* Wi=(const float*)d_in[15]; const float* bi=(const float*)d_in[16];
  const float* Wo2=(const float*)d_in[17];const float* bo2=(const float*)d_in[18];
  const float* g2=(const float*)d_in[19]; const float* b2=(const float*)d_in[20];
  const int* ids  =(const int*)d_in[21];
  const int* amask=(const int*)d_in[22];

  char* p = (char*)d_ws;
  auto alloc = [&](size_t bytes)->char*{ char* r = p; p += (bytes + 255) & ~(size_t)255; return r; };
  float* Hb  = (float*)alloc((size_t)NTOK*NHID*4);
  float* H1  = (float*)alloc((size_t)NTOK*NHID*4);
  float* Xb  = (float*)alloc((size_t)NTOK*NHID*4);
  float* Vb  = (float*)alloc((size_t)NTOK*NHID*4);
  _Float16* Hh  = (_Float16*)alloc((size_t)NTOK*NHID*2);
  _Float16* Hl  = (_Float16*)alloc((size_t)NTOK*NHID*2);
  _Float16* H1h = (_Float16*)alloc((size_t)NTOK*NHID*2);
  _Float16* H1l = (_Float16*)alloc((size_t)NTOK*NHID*2);
  _Float16* FFbh= (_Float16*)alloc((size_t)NTOK*NFF*2);
  _Float16* FFbl= (_Float16*)alloc((size_t)NTOK*NFF*2);
  _Float16* Ctxh= (_Float16*)alloc((size_t)NTOK*NHID*2);
  _Float16* Ctxl= (_Float16*)alloc((size_t)NTOK*NHID*2);
  _Float16* Qhb = (_Float16*)alloc((size_t)NTOK*NHID*2);
  _Float16* Qlb = (_Float16*)alloc((size_t)NTOK*NHID*2);
  _Float16* Khb = (_Float16*)alloc((size_t)NTOK*NHID*2);
  _Float16* Klb = (_Float16*)alloc((size_t)NTOK*NHID*2);
  _Float16* Vth = (_Float16*)alloc((size_t)NTOK*NHID*2);
  _Float16* Vtl = (_Float16*)alloc((size_t)NTOK*NHID*2);
  float* PKb = (float*)alloc((size_t)512*NHID*4);
  float* PQb = (float*)alloc((size_t)512*NHID*4);
  _Float16* PKgh = (_Float16*)alloc((size_t)NHEAD*1024*NDH*2);
  _Float16* PKgl = (_Float16*)alloc((size_t)NHEAD*1024*NDH*2);
  _Float16* PQgh = (_Float16*)alloc((size_t)NHEAD*1024*NDH*2);
  _Float16* PQgl = (_Float16*)alloc((size_t)NHEAD*1024*NDH*2);
  _Float16* CqB = (_Float16*)alloc((size_t)NB*NHEAD*NS*NS*2);
  _Float16* CpB = (_Float16*)alloc((size_t)NB*NHEAD*NS*NS*2);
  _Float16* Rh  = (_Float16*)alloc((size_t)512*NHID*2);
  _Float16* Rl  = (_Float16*)alloc((size_t)512*NHID*2);
  _Float16* WtH = (_Float16*)alloc((size_t)7077888*2);
  _Float16* WtL = (_Float16*)alloc((size_t)7077888*2);

  const size_t WO[6] = {0, 589824, 1179648, 1769472, 2359296, 4718592};

  dim3 blk(256);
  dim3 gRel(1024, NHEAD);
  dim3 gAttn(NS/32, NHEAD, NB);
  dim3 gBand(NS/32, NHEAD, NB);
  dim3 gVt(NS/64, NHEAD, NB);
  dim3 gPrep(48, 96, 6);

  emb_kernel<<<NTOK,blk,0,stream>>>(word_emb,pos_emb,emb_g,emb_b,ids,amask,Hb,Hh,Hl);
  planes_kernel<<<192,blk,0,stream>>>(rel_emb, Rh, Rl, 512*NHID/8);

  for (int l=0; l<NL; l++){
    const float *Wq_l=Wq+(size_t)l*NHID*NHID, *bq_l=bq+(size_t)l*NHID;
    const float *Wk_l=Wk+(size_t)l*NHID*NHID, *bk_l=bk+(size_t)l*NHID;
    const float *Wv_l=Wv+(size_t)l*NHID*NHID, *bv_l=bvv+(size_t)l*NHID;
    const float *Wo_l=Wo+(size_t)l*NHID*NHID, *bo_l=bo+(size_t)l*NHID;
    const float *g1_l=g1+(size_t)l*NHID, *b1_l=b1+(size_t)l*NHID;
    const float *Wi_l=Wi+(size_t)l*NHID*NFF, *bi_l=bi+(size_t)l*NFF;
    const float *Wo2_l=Wo2+(size_t)l*NFF*NHID, *bo2_l=bo2+(size_t)l*NHID;
    const float *g2_l=g2+(size_t)l*NHID, *b2_l=b2+(size_t)l*NHID;

    wprep_kernel<<<gPrep,blk,0,stream>>>(Wq_l,Wk_l,Wv_l,Wo_l,Wi_l,Wo2_l,WtH,WtL);

    // relative position projections + gather/convert
    gemm2<0,64><<<48,blk,0,stream>>>(Rh,Rl, WtH+WO[1],WtL+WO[1], bk_l, nullptr, PKb,nullptr,nullptr, 512,NHID,NHID, 12);
    gemm2<0,64><<<48,blk,0,stream>>>(Rh,Rl, WtH+WO[0],WtL+WO[0], bq_l, nullptr, PQb,nullptr,nullptr, 512,NHID,NHID, 12);
    relgather_kernel<<<gRel,dim3(64),0,stream>>>(PKb, PQb, PKgh, PKgl, PQgh, PQgl);
    // Q,K (f16 hi/lo), V (f32 -> transposed f16 hi/lo)
    gemm2<3,64><<<384,blk,0,stream>>>(Hh,Hl, WtH+WO[0],WtL+WO[0], bq_l, nullptr, nullptr,Qhb,Qlb, NTOK,NHID,NHID, 12);
    gemm2<3,64><<<384,blk,0,stream>>>(Hh,Hl, WtH+WO[1],WtL+WO[1], bk_l, nullptr, nullptr,Khb,Klb, NTOK,NHID,NHID, 12);
    gemm2<0,64><<<384,blk,0,stream>>>(Hh,Hl, WtH+WO[2],WtL+WO[2], bv_l, nullptr, Vb,nullptr,nullptr, NTOK,NHID,NHID, 12);
    vtrans_kernel<<<gVt,blk,0,stream>>>(Vb, Vth, Vtl);
    // banded positional score tables
    cband_kernel<1><<<gBand,blk,0,stream>>>(Qhb, Qlb, PKgh, PKgl, CqB);
    cband_kernel<-1><<<gBand,blk,0,stream>>>(Khb, Klb, PQgh, PQgl, CpB);
    // attention
    attn_mfma<<<gAttn,blk,0,stream>>>(Qhb,Qlb,Khb,Klb,Vth,Vtl,CqB,CpB,amask,Ctxh,Ctxl);
    // output proj + residual, LN1
    gemm2<2,64><<<384,blk,0,stream>>>(Ctxh,Ctxl, WtH+WO[3],WtL+WO[3], bo_l, Hb, Xb,nullptr,nullptr, NTOK,NHID,NHID, 12);
    ln_kernel<<<NTOK,blk,0,stream>>>(Xb, g1_l, b1_l, H1, H1h, H1l);
    // FFN
    gemm2<1,128><<<768,blk,0,stream>>>(H1h,H1l, WtH+WO[4],WtL+WO[4], bi_l, nullptr, nullptr,FFbh,FFbl, NTOK,NFF,NHID, 24);
    gemm2<2,64><<<384,blk,0,stream>>>(FFbh,FFbl, WtH+WO[5],WtL+WO[5], bo2_l, H1, Xb,nullptr,nullptr, NTOK,NHID,NFF, 12);
    // LN2: last layer writes the final output directly
    float* dst = (l==NL-1) ? (float*)d_out : Hb;
    ln_kernel<<<NTOK,blk,0,stream>>>(Xb, g2_l, b2_l, dst, Hh, Hl);
  }
}